// Round 11
// baseline (735.093 us; speedup 1.0000x reference)
//
#include <hip/hip_runtime.h>
#include <hip/hip_bf16.h>

#define N_NODES 100000
#define N_EDGES 600000
#define N_GRAPHS 64
#define D 128

#define NBLK_SCAN ((N_NODES + 255) / 256)  // 391

// ---------------- CSR build ----------------

__global__ void count_deg_k(const int* __restrict__ col, int* __restrict__ cnt) {
    int e = blockIdx.x * blockDim.x + threadIdx.x;
    if (e < N_EDGES) atomicAdd(&cnt[col[e]], 1);
}

__global__ __launch_bounds__(256) void partial_k(const int* __restrict__ cnt,
                                                 int* __restrict__ psum) {
    int i = blockIdx.x * 256 + threadIdx.x;
    int v = (i < N_NODES) ? cnt[i] : 0;
#pragma unroll
    for (int d = 32; d > 0; d >>= 1) v += __shfl_down(v, d, 64);
    __shared__ int ws[4];
    if ((threadIdx.x & 63) == 0) ws[threadIdx.x >> 6] = v;
    __syncthreads();
    if (threadIdx.x == 0) psum[blockIdx.x] = ws[0] + ws[1] + ws[2] + ws[3];
}

__global__ __launch_bounds__(512) void scanpart_k(int* __restrict__ psum) {
    __shared__ int ls[512];
    int t = threadIdx.x;
    int v = (t < NBLK_SCAN) ? psum[t] : 0;
    ls[t] = v;
    __syncthreads();
    for (int d = 1; d < 512; d <<= 1) {
        int u = (t >= d) ? ls[t - d] : 0;
        __syncthreads();
        ls[t] += u;
        __syncthreads();
    }
    if (t < NBLK_SCAN) psum[t] = ls[t] - v;  // exclusive
}

__global__ __launch_bounds__(256) void scan_scatter_k(const int* __restrict__ cnt,
                                                      const int* __restrict__ psum,
                                                      int* __restrict__ start) {
    int b = blockIdx.x, t = threadIdx.x;
    int i = b * 256 + t;
    int v = (i < N_NODES) ? cnt[i] : 0;
    __shared__ int ls[256];
    ls[t] = v;
    __syncthreads();
    for (int d = 1; d < 256; d <<= 1) {
        int u = (t >= d) ? ls[t - d] : 0;
        __syncthreads();
        ls[t] += u;
        __syncthreads();
    }
    int incl = ls[t];
    int off = psum[b];
    if (i < N_NODES) start[i] = off + incl - v;
    if (i == N_NODES - 1) start[N_NODES] = off + incl;
}

__global__ void fill_csr_k(const int* __restrict__ row, const int* __restrict__ col,
                           const int* __restrict__ start, int* __restrict__ fill,
                           int* __restrict__ esrc) {
    int e = blockIdx.x * blockDim.x + threadIdx.x;
    if (e < N_EDGES) {
        int c = col[e];
        int p = atomicAdd(&fill[c], 1);
        esrc[start[c] + p] = row[e];
    }
}

// ---------------- graph segment bounds (batch is sorted) ----------------

__global__ __launch_bounds__(128) void bounds_k(const int* __restrict__ batch,
                                                int* __restrict__ gstart) {
    int g = threadIdx.x;
    if (g > N_GRAPHS) return;
    int lo = 0, hi = N_NODES;
    while (lo < hi) {
        int mid = (lo + hi) >> 1;
        if (batch[mid] < g) lo = mid + 1; else hi = mid;
    }
    gstart[g] = lo;
}

// ---------------- GEMM: out[i][j] = bias[j] + sum_k in[i][k]*W[j][k] ----------------
// Barrier-free, LDS-free: W (64KB) is L2-resident across all 782 blocks; both
// operands stream from cache. a[i] loads broadcast over 16 same-address lanes
// (coalescer dedupes); w[r] loads hit L2-hot lines. 16:1 FMA:load ratio +
// ~3 waves/SIMD hides latency. No __launch_bounds__ min-waves -> no spill.

#define BM 128

__global__ __launch_bounds__(256) void gemm_k(const float* __restrict__ A,
                                              const float* __restrict__ W,
                                              const float* __restrict__ bias,
                                              float* __restrict__ out, int nrows) {
    const int tid = threadIdx.x;
    const int bm0 = blockIdx.x * BM;
    const int tx = tid & 15, ty = tid >> 4;

    float acc[8][8];
#pragma unroll
    for (int i = 0; i < 8; ++i)
#pragma unroll
        for (int r = 0; r < 8; ++r) acc[i][r] = 0.f;

    float bv[8];
#pragma unroll
    for (int r = 0; r < 8; ++r) bv[r] = bias[8 * tx + r];

    // clamped A-row offsets (tail block reads stay in-buffer; garbage rows never stored)
    int aoff[8];
#pragma unroll
    for (int i = 0; i < 8; ++i)
        aoff[i] = min(bm0 + 8 * ty + i, nrows - 1) * D;

#pragma unroll 2
    for (int kb = 0; kb < D; kb += 4) {
        float4 a[8], w[8];
#pragma unroll
        for (int i = 0; i < 8; ++i)
            a[i] = *reinterpret_cast<const float4*>(&A[(size_t)(aoff[i] + kb)]);
#pragma unroll
        for (int r = 0; r < 8; ++r)
            w[r] = *reinterpret_cast<const float4*>(&W[(8 * tx + r) * D + kb]);
#pragma unroll
        for (int i = 0; i < 8; ++i)
#pragma unroll
            for (int r = 0; r < 8; ++r) {
                acc[i][r] = fmaf(a[i].x, w[r].x, acc[i][r]);
                acc[i][r] = fmaf(a[i].y, w[r].y, acc[i][r]);
                acc[i][r] = fmaf(a[i].z, w[r].z, acc[i][r]);
                acc[i][r] = fmaf(a[i].w, w[r].w, acc[i][r]);
            }
    }

#pragma unroll
    for (int i = 0; i < 8; ++i) {
        int grow = bm0 + ty * 8 + i;
        if (grow >= nrows) continue;
        float4 o0 = make_float4(acc[i][0] + bv[0], acc[i][1] + bv[1],
                                acc[i][2] + bv[2], acc[i][3] + bv[3]);
        float4 o1 = make_float4(acc[i][4] + bv[4], acc[i][5] + bv[5],
                                acc[i][6] + bv[6], acc[i][7] + bv[7]);
        *reinterpret_cast<float4*>(&out[(size_t)grow * D + tx * 8]) = o0;
        *reinterpret_cast<float4*>(&out[(size_t)grow * D + tx * 8 + 4]) = o1;
    }
}

// ---------------- Aggregation (round-8 known-good: one node per 128-thread block) ----

__global__ __launch_bounds__(128) void aggregate_k(const float* __restrict__ t,
                                                   const int* __restrict__ start,
                                                   const int* __restrict__ esrc,
                                                   float* __restrict__ out, int do_relu) {
    int node = blockIdx.x;
    int d = threadIdx.x;
    int s = start[node], e = start[node + 1];
    float acc = t[(size_t)node * D + d];  // self loop
    int i = s;
    for (; i + 1 < e; i += 2) {
        int s0 = esrc[i], s1 = esrc[i + 1];
        float a = t[(size_t)s0 * D + d];
        float b = t[(size_t)s1 * D + d];
        acc += a + b;
    }
    if (i < e) acc += t[(size_t)esrc[i] * D + d];
    if (do_relu) acc = fmaxf(acc, 0.f);
    out[(size_t)node * D + d] = acc;
}

// ---------------- Collapsed layer 4 + pool + head ----------------
// logit_g = (1/c_g) * sum_{i in g} [ s[i] + sum_{src->i} s[src] + (1+deg_i)*beta ] + bc
// where s[i] = h3[i] . v,  v = Wc @ W4,  beta = Wc . b4.

__global__ __launch_bounds__(128) void vbeta_k(const float* __restrict__ W4,
                                               const float* __restrict__ b4,
                                               const float* __restrict__ Wc,
                                               float* __restrict__ vbeta) {
    int k = threadIdx.x;
    float acc = 0.f;
    for (int j = 0; j < D; ++j) acc = fmaf(Wc[j], W4[j * D + k], acc);
    vbeta[k] = acc;
    __shared__ float red[128];
    red[k] = Wc[k] * b4[k];
    __syncthreads();
    for (int st = 64; st > 0; st >>= 1) {
        if (k < st) red[k] += red[k + st];
        __syncthreads();
    }
    if (k == 0) vbeta[D] = red[0];
}

__global__ __launch_bounds__(256) void matvec_k(const float* __restrict__ h,
                                                const float* __restrict__ vbeta,
                                                float* __restrict__ s) {
    int wid = threadIdx.x >> 6, lane = threadIdx.x & 63;
    int row = blockIdx.x * 4 + wid;
    const float2 hv = *reinterpret_cast<const float2*>(&h[(size_t)row * D + lane * 2]);
    const float2 vv = *reinterpret_cast<const float2*>(&vbeta[lane * 2]);
    float dot = fmaf(hv.x, vv.x, hv.y * vv.y);
#pragma unroll
    for (int d = 32; d > 0; d >>= 1) dot += __shfl_down(dot, d, 64);
    if (lane == 0) s[row] = dot;
}

__global__ __launch_bounds__(256) void sagg_k(const float* __restrict__ s,
                                              const int* __restrict__ start,
                                              const int* __restrict__ esrc,
                                              const float* __restrict__ vbeta,
                                              float* __restrict__ a) {
    int i = blockIdx.x * 256 + threadIdx.x;
    if (i >= N_NODES) return;
    int s0 = start[i], s1 = start[i + 1];
    float beta = vbeta[D];
    float acc = s[i] + (float)(1 + s1 - s0) * beta;
    for (int e = s0; e < s1; ++e) acc += s[esrc[e]];
    a[i] = acc;
}

__global__ __launch_bounds__(256) void spool_k(const float* __restrict__ a,
                                               const int* __restrict__ gstart,
                                               const float* __restrict__ bc,
                                               float* __restrict__ out) {
    int g = blockIdx.x;
    int lo = gstart[g], hi = gstart[g + 1];
    float acc = 0.f;
    for (int i = lo + threadIdx.x; i < hi; i += 256) acc += a[i];
    __shared__ float red[256];
    red[threadIdx.x] = acc;
    __syncthreads();
    for (int st = 128; st > 0; st >>= 1) {
        if (threadIdx.x < st) red[threadIdx.x] += red[threadIdx.x + st];
        __syncthreads();
    }
    if (threadIdx.x == 0) {
        float c = (float)max(hi - lo, 1);
        out[g] = 1.f / (1.f + expf(-(red[0] / c + bc[0])));
    }
}

// ---------------- Launch ----------------

extern "C" void kernel_launch(void* const* d_in, const int* in_sizes, int n_in,
                              void* d_out, int out_size, void* d_ws, size_t ws_size,
                              hipStream_t stream) {
    const float* x   = (const float*)d_in[0];
    const int* ei    = (const int*)d_in[1];
    const int* batch = (const int*)d_in[2];
    const float* W1  = (const float*)d_in[3];
    const float* b1  = (const float*)d_in[4];
    const float* W2  = (const float*)d_in[5];
    const float* b2  = (const float*)d_in[6];
    const float* W3  = (const float*)d_in[7];
    const float* b3  = (const float*)d_in[8];
    const float* W4  = (const float*)d_in[9];
    const float* b4  = (const float*)d_in[10];
    const float* Wc  = (const float*)d_in[11];
    const float* bc  = (const float*)d_in[12];
    float* out = (float*)d_out;

    const int* row = ei;             // sources
    const int* col = ei + N_EDGES;   // targets

    char* p = (char*)d_ws;
    float* t = (float*)p;      p += (size_t)N_NODES * D * 4;   // 51.2 MB
    float* h = (float*)p;      p += (size_t)N_NODES * D * 4;   // 51.2 MB
    int* esrc = (int*)p;       p += (size_t)N_EDGES * 4;
    int* cstart = (int*)p;     p += ((N_NODES + 1) * 4 + 15) / 16 * 16;
    int* cfill = (int*)p;      p += (size_t)N_NODES * 4;
    int* psum = (int*)p;       p += ((NBLK_SCAN + 3) / 4) * 16;
    int* gstart = (int*)p;     p += 256;

    // scalar-path scratch lives in t (free after layer-3 aggregate consumes it)
    float* vbeta = t;
    float* s_arr = t + 256;
    float* a_arr = t + 256 + N_NODES;

    // ---- CSR build ----
    hipMemsetAsync(cfill, 0, (size_t)N_NODES * 4, stream);
    count_deg_k<<<(N_EDGES + 255) / 256, 256, 0, stream>>>(col, cfill);
    partial_k<<<NBLK_SCAN, 256, 0, stream>>>(cfill, psum);
    scanpart_k<<<1, 512, 0, stream>>>(psum);
    scan_scatter_k<<<NBLK_SCAN, 256, 0, stream>>>(cfill, psum, cstart);
    hipMemsetAsync(cfill, 0, (size_t)N_NODES * 4, stream);
    fill_csr_k<<<(N_EDGES + 255) / 256, 256, 0, stream>>>(row, col, cstart, cfill, esrc);

    // ---- graph bounds ----
    bounds_k<<<1, 128, 0, stream>>>(batch, gstart);

    const int ggrid = (N_NODES + BM - 1) / BM;  // 782

    // ---- Layers 1-3 ----
    gemm_k<<<ggrid, 256, 0, stream>>>(x, W1, b1, t, N_NODES);
    aggregate_k<<<N_NODES, 128, 0, stream>>>(t, cstart, esrc, h, 1);
    gemm_k<<<ggrid, 256, 0, stream>>>(h, W2, b2, t, N_NODES);
    aggregate_k<<<N_NODES, 128, 0, stream>>>(t, cstart, esrc, h, 1);
    gemm_k<<<ggrid, 256, 0, stream>>>(h, W3, b3, t, N_NODES);
    aggregate_k<<<N_NODES, 128, 0, stream>>>(t, cstart, esrc, h, 1);

    // ---- Collapsed layer 4 + pool + head (reads h = h3) ----
    vbeta_k<<<1, 128, 0, stream>>>(W4, b4, Wc, vbeta);
    matvec_k<<<N_NODES / 4, 256, 0, stream>>>(h, vbeta, s_arr);
    sagg_k<<<(N_NODES + 255) / 256, 256, 0, stream>>>(s_arr, cstart, esrc, vbeta, a_arr);
    spool_k<<<N_GRAPHS, 256, 0, stream>>>(a_arr, gstart, bc, out);
}

// Round 12
// 455.358 us; speedup vs baseline: 1.6143x; 1.6143x over previous
//
#include <hip/hip_runtime.h>
#include <hip/hip_bf16.h>

#define N_NODES 100000
#define N_EDGES 600000
#define N_GRAPHS 64
#define D 128

#define NBLK_SCAN ((N_NODES + 255) / 256)  // 391

// ---------------- CSR build ----------------

__global__ void count_deg_k(const int* __restrict__ col, int* __restrict__ cnt) {
    int e = blockIdx.x * blockDim.x + threadIdx.x;
    if (e < N_EDGES) atomicAdd(&cnt[col[e]], 1);
}

__global__ __launch_bounds__(256) void partial_k(const int* __restrict__ cnt,
                                                 int* __restrict__ psum) {
    int i = blockIdx.x * 256 + threadIdx.x;
    int v = (i < N_NODES) ? cnt[i] : 0;
#pragma unroll
    for (int d = 32; d > 0; d >>= 1) v += __shfl_down(v, d, 64);
    __shared__ int ws[4];
    if ((threadIdx.x & 63) == 0) ws[threadIdx.x >> 6] = v;
    __syncthreads();
    if (threadIdx.x == 0) psum[blockIdx.x] = ws[0] + ws[1] + ws[2] + ws[3];
}

__global__ __launch_bounds__(512) void scanpart_k(int* __restrict__ psum) {
    __shared__ int ls[512];
    int t = threadIdx.x;
    int v = (t < NBLK_SCAN) ? psum[t] : 0;
    ls[t] = v;
    __syncthreads();
    for (int d = 1; d < 512; d <<= 1) {
        int u = (t >= d) ? ls[t - d] : 0;
        __syncthreads();
        ls[t] += u;
        __syncthreads();
    }
    if (t < NBLK_SCAN) psum[t] = ls[t] - v;  // exclusive
}

__global__ __launch_bounds__(256) void scan_scatter_k(const int* __restrict__ cnt,
                                                      const int* __restrict__ psum,
                                                      int* __restrict__ start) {
    int b = blockIdx.x, t = threadIdx.x;
    int i = b * 256 + t;
    int v = (i < N_NODES) ? cnt[i] : 0;
    __shared__ int ls[256];
    ls[t] = v;
    __syncthreads();
    for (int d = 1; d < 256; d <<= 1) {
        int u = (t >= d) ? ls[t - d] : 0;
        __syncthreads();
        ls[t] += u;
        __syncthreads();
    }
    int incl = ls[t];
    int off = psum[b];
    if (i < N_NODES) start[i] = off + incl - v;
    if (i == N_NODES - 1) start[N_NODES] = off + incl;
}

__global__ void fill_csr_k(const int* __restrict__ row, const int* __restrict__ col,
                           const int* __restrict__ start, int* __restrict__ fill,
                           int* __restrict__ esrc) {
    int e = blockIdx.x * blockDim.x + threadIdx.x;
    if (e < N_EDGES) {
        int c = col[e];
        int p = atomicAdd(&fill[c], 1);
        esrc[start[c] + p] = row[e];
    }
}

// ---------------- graph segment bounds (batch is sorted) ----------------

__global__ __launch_bounds__(128) void bounds_k(const int* __restrict__ batch,
                                                int* __restrict__ gstart) {
    int g = threadIdx.x;
    if (g > N_GRAPHS) return;
    int lo = 0, hi = N_NODES;
    while (lo < hi) {
        int mid = (lo + hi) >> 1;
        if (batch[mid] < g) lo = mid + 1; else hi = mid;
    }
    gstart[g] = lo;
}

// ---------------- GEMM (round-8 measured-best: swizzled gload_lds, (256,2)) ----
// out[i][j] = bias[j] + sum_k in[i][k]*W[j][k]
// LDS tile [128 rows][32 floats]; slot c4' of row holds global chunk
// c4'^s4(row), s4(row) = ((row>>3)^row)&7. Reads:
//   A row 8ty+i -> slot c4 ^ ((ty^i)&7)  : 4 broadcast addrs/wave -> free
//   W row 8tx+r -> slot c4 ^ ((tx^r)&7)  : 2-way over 16 tx -> free (m136)

#define BM 128
#define KT 32

__device__ __forceinline__ void stage32(const float* __restrict__ G, float* lds,
                                        int grow0, int kb, int nrows, int tid) {
    int l = tid & 63, w = tid >> 6;
#pragma unroll
    for (int i = 0; i < 4; ++i) {
        int f = (w + i * 4) * 64 + l;  // float4 task 0..1023
        int row = f >> 3, c4 = f & 7;
        int s4 = ((row >> 3) ^ row) & 7;
        const float* gp = G + (size_t)(grow0 + row) * D + kb + ((c4 ^ s4) << 2);
        float* lp = lds + (w + i * 4) * 256;  // wave-uniform; HW adds lane*16B
        if (grow0 + row < nrows)
            __builtin_amdgcn_global_load_lds(
                (const __attribute__((address_space(1))) void*)gp,
                (__attribute__((address_space(3))) void*)lp, 16, 0, 0);
    }
}

__global__ __launch_bounds__(256, 2) void gemm_k(const float* __restrict__ A,
                                                 const float* __restrict__ W,
                                                 const float* __restrict__ bias,
                                                 float* __restrict__ out, int nrows) {
    __shared__ float sA[BM * KT];  // 16KB
    __shared__ float sW[BM * KT];  // 16KB
    const int tid = threadIdx.x;
    const int bm0 = blockIdx.x * BM;
    const int tx = tid & 15, ty = tid >> 4;

    float acc[8][8];
#pragma unroll
    for (int i = 0; i < 8; ++i)
#pragma unroll
        for (int r = 0; r < 8; ++r) acc[i][r] = 0.f;

    float bv[8];
#pragma unroll
    for (int r = 0; r < 8; ++r) bv[r] = bias[8 * tx + r];

    for (int kt = 0; kt < D / KT; ++kt) {
        stage32(A, sA, bm0, kt * KT, nrows, tid);
        stage32(W, sW, 0, kt * KT, D, tid);
        __syncthreads();  // drains vmcnt (gload_lds) for all waves
#pragma unroll
        for (int c4 = 0; c4 < 8; ++c4) {
            float4 a[8], w[8];
#pragma unroll
            for (int i = 0; i < 8; ++i)
                a[i] = *reinterpret_cast<const float4*>(
                    &sA[(8 * ty + i) * KT + ((c4 ^ ((ty ^ i) & 7)) << 2)]);
#pragma unroll
            for (int r = 0; r < 8; ++r)
                w[r] = *reinterpret_cast<const float4*>(
                    &sW[(8 * tx + r) * KT + ((c4 ^ ((tx ^ r) & 7)) << 2)]);
#pragma unroll
            for (int i = 0; i < 8; ++i)
#pragma unroll
                for (int r = 0; r < 8; ++r) {
                    acc[i][r] = fmaf(a[i].x, w[r].x, acc[i][r]);
                    acc[i][r] = fmaf(a[i].y, w[r].y, acc[i][r]);
                    acc[i][r] = fmaf(a[i].z, w[r].z, acc[i][r]);
                    acc[i][r] = fmaf(a[i].w, w[r].w, acc[i][r]);
                }
        }
        __syncthreads();  // protect LDS before next stage
    }

#pragma unroll
    for (int i = 0; i < 8; ++i) {
        int grow = bm0 + ty * 8 + i;
        if (grow >= nrows) continue;
        float4 o0 = make_float4(acc[i][0] + bv[0], acc[i][1] + bv[1],
                                acc[i][2] + bv[2], acc[i][3] + bv[3]);
        float4 o1 = make_float4(acc[i][4] + bv[4], acc[i][5] + bv[5],
                                acc[i][6] + bv[6], acc[i][7] + bv[7]);
        *reinterpret_cast<float4*>(&out[(size_t)grow * D + tx * 8]) = o0;
        *reinterpret_cast<float4*>(&out[(size_t)grow * D + tx * 8 + 4]) = o1;
    }
}

// ---------------- Aggregation: out[i] = t[i] + sum_{e: col==i} t[src[e]] ----------------
// One wave per node (4 waves/block, no __syncthreads), float2 per lane:
// each gather = one 512B wave-coalesced request, half the instructions of
// the 128-thread/4B variant.

__global__ __launch_bounds__(256) void aggregate_k(const float* __restrict__ t,
                                                   const int* __restrict__ start,
                                                   const int* __restrict__ esrc,
                                                   float* __restrict__ out, int do_relu) {
    const int wv = threadIdx.x >> 6, l = threadIdx.x & 63;
    const int node = blockIdx.x * 4 + wv;
    if (node >= N_NODES) return;
    const int s = start[node], e = start[node + 1];
    const size_t base = ((size_t)node << 7) + 2 * l;
    float2 acc = *reinterpret_cast<const float2*>(t + base);  // self loop
    int i = s;
    for (; i + 1 < e; i += 2) {
        const float2 v0 = *reinterpret_cast<const float2*>(t + (((size_t)esrc[i] << 7) + 2 * l));
        const float2 v1 = *reinterpret_cast<const float2*>(t + (((size_t)esrc[i + 1] << 7) + 2 * l));
        acc.x += v0.x + v1.x;
        acc.y += v0.y + v1.y;
    }
    if (i < e) {
        const float2 v = *reinterpret_cast<const float2*>(t + (((size_t)esrc[i] << 7) + 2 * l));
        acc.x += v.x;
        acc.y += v.y;
    }
    if (do_relu) {
        acc.x = fmaxf(acc.x, 0.f);
        acc.y = fmaxf(acc.y, 0.f);
    }
    *reinterpret_cast<float2*>(out + base) = acc;
}

// ---------------- Collapsed layer 4 + pool + head ----------------
// logit_g = (1/c_g) * sum_{i in g} [ s[i] + sum_{src->i} s[src] + (1+deg_i)*beta ] + bc
// where s[i] = h3[i] . v,  v = Wc @ W4,  beta = Wc . b4.

__global__ __launch_bounds__(128) void vbeta_k(const float* __restrict__ W4,
                                               const float* __restrict__ b4,
                                               const float* __restrict__ Wc,
                                               float* __restrict__ vbeta) {
    int k = threadIdx.x;
    float acc = 0.f;
    for (int j = 0; j < D; ++j) acc = fmaf(Wc[j], W4[j * D + k], acc);
    vbeta[k] = acc;
    __shared__ float red[128];
    red[k] = Wc[k] * b4[k];
    __syncthreads();
    for (int st = 64; st > 0; st >>= 1) {
        if (k < st) red[k] += red[k + st];
        __syncthreads();
    }
    if (k == 0) vbeta[D] = red[0];
}

__global__ __launch_bounds__(256) void matvec_k(const float* __restrict__ h,
                                                const float* __restrict__ vbeta,
                                                float* __restrict__ s) {
    int wid = threadIdx.x >> 6, lane = threadIdx.x & 63;
    int row = blockIdx.x * 4 + wid;
    const float2 hv = *reinterpret_cast<const float2*>(&h[(size_t)row * D + lane * 2]);
    const float2 vv = *reinterpret_cast<const float2*>(&vbeta[lane * 2]);
    float dot = fmaf(hv.x, vv.x, hv.y * vv.y);
#pragma unroll
    for (int d = 32; d > 0; d >>= 1) dot += __shfl_down(dot, d, 64);
    if (lane == 0) s[row] = dot;
}

__global__ __launch_bounds__(256) void sagg_k(const float* __restrict__ s,
                                              const int* __restrict__ start,
                                              const int* __restrict__ esrc,
                                              const float* __restrict__ vbeta,
                                              float* __restrict__ a) {
    int i = blockIdx.x * 256 + threadIdx.x;
    if (i >= N_NODES) return;
    int s0 = start[i], s1 = start[i + 1];
    float beta = vbeta[D];
    float acc = s[i] + (float)(1 + s1 - s0) * beta;
    for (int e = s0; e < s1; ++e) acc += s[esrc[e]];
    a[i] = acc;
}

__global__ __launch_bounds__(256) void spool_k(const float* __restrict__ a,
                                               const int* __restrict__ gstart,
                                               const float* __restrict__ bc,
                                               float* __restrict__ out) {
    int g = blockIdx.x;
    int lo = gstart[g], hi = gstart[g + 1];
    float acc = 0.f;
    for (int i = lo + threadIdx.x; i < hi; i += 256) acc += a[i];
    __shared__ float red[256];
    red[threadIdx.x] = acc;
    __syncthreads();
    for (int st = 128; st > 0; st >>= 1) {
        if (threadIdx.x < st) red[threadIdx.x] += red[threadIdx.x + st];
        __syncthreads();
    }
    if (threadIdx.x == 0) {
        float c = (float)max(hi - lo, 1);
        out[g] = 1.f / (1.f + expf(-(red[0] / c + bc[0])));
    }
}

// ---------------- Launch ----------------

extern "C" void kernel_launch(void* const* d_in, const int* in_sizes, int n_in,
                              void* d_out, int out_size, void* d_ws, size_t ws_size,
                              hipStream_t stream) {
    const float* x   = (const float*)d_in[0];
    const int* ei    = (const int*)d_in[1];
    const int* batch = (const int*)d_in[2];
    const float* W1  = (const float*)d_in[3];
    const float* b1  = (const float*)d_in[4];
    const float* W2  = (const float*)d_in[5];
    const float* b2  = (const float*)d_in[6];
    const float* W3  = (const float*)d_in[7];
    const float* b3  = (const float*)d_in[8];
    const float* W4  = (const float*)d_in[9];
    const float* b4  = (const float*)d_in[10];
    const float* Wc  = (const float*)d_in[11];
    const float* bc  = (const float*)d_in[12];
    float* out = (float*)d_out;

    const int* row = ei;             // sources
    const int* col = ei + N_EDGES;   // targets

    char* p = (char*)d_ws;
    float* t = (float*)p;      p += (size_t)N_NODES * D * 4;   // 51.2 MB
    float* h = (float*)p;      p += (size_t)N_NODES * D * 4;   // 51.2 MB
    int* esrc = (int*)p;       p += (size_t)N_EDGES * 4;
    int* cstart = (int*)p;     p += ((N_NODES + 1) * 4 + 15) / 16 * 16;
    int* cfill = (int*)p;      p += (size_t)N_NODES * 4;
    int* psum = (int*)p;       p += ((NBLK_SCAN + 3) / 4) * 16;
    int* gstart = (int*)p;     p += 256;

    // scalar-path scratch lives in t (free after layer-3 aggregate consumes it)
    float* vbeta = t;
    float* s_arr = t + 256;
    float* a_arr = t + 256 + N_NODES;

    // ---- CSR build ----
    hipMemsetAsync(cfill, 0, (size_t)N_NODES * 4, stream);
    count_deg_k<<<(N_EDGES + 255) / 256, 256, 0, stream>>>(col, cfill);
    partial_k<<<NBLK_SCAN, 256, 0, stream>>>(cfill, psum);
    scanpart_k<<<1, 512, 0, stream>>>(psum);
    scan_scatter_k<<<NBLK_SCAN, 256, 0, stream>>>(cfill, psum, cstart);
    hipMemsetAsync(cfill, 0, (size_t)N_NODES * 4, stream);
    fill_csr_k<<<(N_EDGES + 255) / 256, 256, 0, stream>>>(row, col, cstart, cfill, esrc);

    // ---- graph bounds ----
    bounds_k<<<1, 128, 0, stream>>>(batch, gstart);

    const int ggrid = (N_NODES + BM - 1) / BM;  // 782
    const int agrid = (N_NODES + 3) / 4;        // 25000

    // ---- Layers 1-3 ----
    gemm_k<<<ggrid, 256, 0, stream>>>(x, W1, b1, t, N_NODES);
    aggregate_k<<<agrid, 256, 0, stream>>>(t, cstart, esrc, h, 1);
    gemm_k<<<ggrid, 256, 0, stream>>>(h, W2, b2, t, N_NODES);
    aggregate_k<<<agrid, 256, 0, stream>>>(t, cstart, esrc, h, 1);
    gemm_k<<<ggrid, 256, 0, stream>>>(h, W3, b3, t, N_NODES);
    aggregate_k<<<agrid, 256, 0, stream>>>(t, cstart, esrc, h, 1);

    // ---- Collapsed layer 4 + pool + head (reads h = h3) ----
    vbeta_k<<<1, 128, 0, stream>>>(W4, b4, Wc, vbeta);
    matvec_k<<<N_NODES / 4, 256, 0, stream>>>(h, vbeta, s_arr);
    sagg_k<<<(N_NODES + 255) / 256, 256, 0, stream>>>(s_arr, cstart, esrc, vbeta, a_arr);
    spool_k<<<N_GRAPHS, 256, 0, stream>>>(a_arr, gstart, bc, out);
}

// Round 13
// 443.223 us; speedup vs baseline: 1.6585x; 1.0274x over previous
//
#include <hip/hip_runtime.h>
#include <hip/hip_bf16.h>

#define N_NODES 100000
#define N_EDGES 600000
#define N_GRAPHS 64
#define D 128

#define NBLK_SCAN ((N_NODES + 255) / 256)  // 391

typedef __attribute__((ext_vector_type(8))) short short8v;
typedef __attribute__((ext_vector_type(4))) float float4v;

__device__ __forceinline__ unsigned short f2bf(float f) {
    unsigned int u = __float_as_uint(f);
    return (unsigned short)((u + 0x7FFF + ((u >> 16) & 1)) >> 16);  // RNE
}
__device__ __forceinline__ float bf2f(unsigned short h) {
    return __uint_as_float(((unsigned int)h) << 16);
}

// ---------------- CSR build ----------------

__global__ void count_deg_k(const int* __restrict__ col, int* __restrict__ cnt) {
    int e = blockIdx.x * blockDim.x + threadIdx.x;
    if (e < N_EDGES) atomicAdd(&cnt[col[e]], 1);
}

__global__ __launch_bounds__(256) void partial_k(const int* __restrict__ cnt,
                                                 int* __restrict__ psum) {
    int i = blockIdx.x * 256 + threadIdx.x;
    int v = (i < N_NODES) ? cnt[i] : 0;
#pragma unroll
    for (int d = 32; d > 0; d >>= 1) v += __shfl_down(v, d, 64);
    __shared__ int ws[4];
    if ((threadIdx.x & 63) == 0) ws[threadIdx.x >> 6] = v;
    __syncthreads();
    if (threadIdx.x == 0) psum[blockIdx.x] = ws[0] + ws[1] + ws[2] + ws[3];
}

__global__ __launch_bounds__(512) void scanpart_k(int* __restrict__ psum) {
    __shared__ int ls[512];
    int t = threadIdx.x;
    int v = (t < NBLK_SCAN) ? psum[t] : 0;
    ls[t] = v;
    __syncthreads();
    for (int d = 1; d < 512; d <<= 1) {
        int u = (t >= d) ? ls[t - d] : 0;
        __syncthreads();
        ls[t] += u;
        __syncthreads();
    }
    if (t < NBLK_SCAN) psum[t] = ls[t] - v;  // exclusive
}

__global__ __launch_bounds__(256) void scan_scatter_k(const int* __restrict__ cnt,
                                                      const int* __restrict__ psum,
                                                      int* __restrict__ start) {
    int b = blockIdx.x, t = threadIdx.x;
    int i = b * 256 + t;
    int v = (i < N_NODES) ? cnt[i] : 0;
    __shared__ int ls[256];
    ls[t] = v;
    __syncthreads();
    for (int d = 1; d < 256; d <<= 1) {
        int u = (t >= d) ? ls[t - d] : 0;
        __syncthreads();
        ls[t] += u;
        __syncthreads();
    }
    int incl = ls[t];
    int off = psum[b];
    if (i < N_NODES) start[i] = off + incl - v;
    if (i == N_NODES - 1) start[N_NODES] = off + incl;
}

__global__ void fill_csr_k(const int* __restrict__ row, const int* __restrict__ col,
                           const int* __restrict__ start, int* __restrict__ fill,
                           int* __restrict__ esrc) {
    int e = blockIdx.x * blockDim.x + threadIdx.x;
    if (e < N_EDGES) {
        int c = col[e];
        int p = atomicAdd(&fill[c], 1);
        esrc[start[c] + p] = row[e];
    }
}

// ---------------- graph segment bounds (batch is sorted) ----------------

__global__ __launch_bounds__(128) void bounds_k(const int* __restrict__ batch,
                                                int* __restrict__ gstart) {
    int g = threadIdx.x;
    if (g > N_GRAPHS) return;
    int lo = 0, hi = N_NODES;
    while (lo < hi) {
        int mid = (lo + hi) >> 1;
        if (batch[mid] < g) lo = mid + 1; else hi = mid;
    }
    gstart[g] = lo;
}

// ---------------- f32 -> (bf16 hi, bf16 lo) split ----------------

__global__ __launch_bounds__(256) void split_k(const float* __restrict__ in,
                                               unsigned short* __restrict__ hi,
                                               unsigned short* __restrict__ lo, int n4) {
    int i = blockIdx.x * 256 + threadIdx.x;
    if (i >= n4) return;
    float4 v = reinterpret_cast<const float4*>(in)[i];
    ushort4 h, l;
    h.x = f2bf(v.x); l.x = f2bf(v.x - bf2f(h.x));
    h.y = f2bf(v.y); l.y = f2bf(v.y - bf2f(h.y));
    h.z = f2bf(v.z); l.z = f2bf(v.z - bf2f(h.z));
    h.w = f2bf(v.w); l.w = f2bf(v.w - bf2f(h.w));
    reinterpret_cast<ushort4*>(hi)[i] = h;
    reinterpret_cast<ushort4*>(lo)[i] = l;
}

// ---------------- Split-bf16 MFMA GEMM ----------------
// out[i][j] = bias[j] + sum_k (Ahi+Alo)[i][k]*(Whi+Wlo)[j][k]  (4 mfma terms,
// f32 accumulate; representation error ~2^-18 per operand).
// mfma_f32_16x16x32_bf16: A/B frag = 8 bf16/lane, non-k dim = lane&15,
// k = (lane>>4)*8 + j (same packing both operands -> any internal k-perm
// cancels). C/D: row=(lane>>4)*4+reg, col=lane&15 (m89/m91-verified).
// Operands load DIRECT from global (A rows read once; W 64KB L2-hot).
// No barriers: epilogue de-scatters acc through per-wave-private LDS.

#define BM 128

__global__ __launch_bounds__(256) void gemm_mfma_k(
    const unsigned short* __restrict__ Ahi, const unsigned short* __restrict__ Alo,
    const unsigned short* __restrict__ Whi, const unsigned short* __restrict__ Wlo,
    const float* __restrict__ bias, float* __restrict__ out, int nrows) {
    __shared__ float swp[4][32][132];  // 67.6KB, per-wave-private slices
    const int tid = threadIdx.x, l = tid & 63, wv = tid >> 6;
    const int bm0 = blockIdx.x * BM;
    const int g = l >> 4, li = l & 15;

    float4v acc[2][8];
#pragma unroll
    for (int rg = 0; rg < 2; ++rg)
#pragma unroll
        for (int cg = 0; cg < 8; ++cg) acc[rg][cg] = (float4v){0.f, 0.f, 0.f, 0.f};

    size_t abase[2];
#pragma unroll
    for (int rg = 0; rg < 2; ++rg)
        abase[rg] = (size_t)min(bm0 + wv * 32 + rg * 16 + li, nrows - 1) * D + g * 8;

#pragma unroll
    for (int kk = 0; kk < 4; ++kk) {
        const int k0 = kk * 32;
        short8v ah[2], al[2];
#pragma unroll
        for (int rg = 0; rg < 2; ++rg) {
            ah[rg] = *reinterpret_cast<const short8v*>(Ahi + abase[rg] + k0);
            al[rg] = *reinterpret_cast<const short8v*>(Alo + abase[rg] + k0);
        }
#pragma unroll
        for (int cg = 0; cg < 8; ++cg) {
            const size_t wb = (size_t)(cg * 16 + li) * D + g * 8 + k0;
            short8v wh = *reinterpret_cast<const short8v*>(Whi + wb);
            short8v wl = *reinterpret_cast<const short8v*>(Wlo + wb);
#pragma unroll
            for (int rg = 0; rg < 2; ++rg) {
                acc[rg][cg] = __builtin_amdgcn_mfma_f32_16x16x32_bf16(ah[rg], wh, acc[rg][cg], 0, 0, 0);
                acc[rg][cg] = __builtin_amdgcn_mfma_f32_16x16x32_bf16(al[rg], wh, acc[rg][cg], 0, 0, 0);
                acc[rg][cg] = __builtin_amdgcn_mfma_f32_16x16x32_bf16(ah[rg], wl, acc[rg][cg], 0, 0, 0);
                acc[rg][cg] = __builtin_amdgcn_mfma_f32_16x16x32_bf16(al[rg], wl, acc[rg][cg], 0, 0, 0);
            }
        }
    }

    // epilogue: frag layout -> row-major via per-wave LDS slice (no barrier)
#pragma unroll
    for (int rg = 0; rg < 2; ++rg)
#pragma unroll
        for (int cg = 0; cg < 8; ++cg)
#pragma unroll
            for (int r = 0; r < 4; ++r)
                swp[wv][rg * 16 + g * 4 + r][cg * 16 + li] = acc[rg][cg][r];

    const int c4 = l & 31, rh = l >> 5;
    const float4 bias_v = *reinterpret_cast<const float4*>(&bias[c4 * 4]);
#pragma unroll
    for (int it = 0; it < 16; ++it) {
        int rowl = it * 2 + rh;
        int grow = bm0 + wv * 32 + rowl;
        if (grow < nrows) {
            float4 v = *reinterpret_cast<const float4*>(&swp[wv][rowl][c4 * 4]);
            v.x += bias_v.x; v.y += bias_v.y; v.z += bias_v.z; v.w += bias_v.w;
            *reinterpret_cast<float4*>(&out[(size_t)grow * D + c4 * 4]) = v;
        }
    }
}

// ---------------- Aggregation: (t f32 gather) -> bf16 hi/lo pair ----------------
// out_{hi,lo}[i] = split( relu_opt( t[i] + sum_{e: col==i} t[src[e]] ) )
// One wave per node, float2 per lane.

__global__ __launch_bounds__(256) void aggregate_k(const float* __restrict__ t,
                                                   const int* __restrict__ start,
                                                   const int* __restrict__ esrc,
                                                   unsigned short* __restrict__ ohi,
                                                   unsigned short* __restrict__ olo,
                                                   int do_relu) {
    const int wv = threadIdx.x >> 6, l = threadIdx.x & 63;
    const int node = blockIdx.x * 4 + wv;
    if (node >= N_NODES) return;
    const int s = start[node], e = start[node + 1];
    const size_t base = ((size_t)node << 7) + 2 * l;
    float2 acc = *reinterpret_cast<const float2*>(t + base);  // self loop
    int i = s;
    for (; i + 1 < e; i += 2) {
        const float2 v0 = *reinterpret_cast<const float2*>(t + (((size_t)esrc[i] << 7) + 2 * l));
        const float2 v1 = *reinterpret_cast<const float2*>(t + (((size_t)esrc[i + 1] << 7) + 2 * l));
        acc.x += v0.x + v1.x;
        acc.y += v0.y + v1.y;
    }
    if (i < e) {
        const float2 v = *reinterpret_cast<const float2*>(t + (((size_t)esrc[i] << 7) + 2 * l));
        acc.x += v.x;
        acc.y += v.y;
    }
    if (do_relu) {
        acc.x = fmaxf(acc.x, 0.f);
        acc.y = fmaxf(acc.y, 0.f);
    }
    unsigned short hx = f2bf(acc.x), hy = f2bf(acc.y);
    unsigned short lx = f2bf(acc.x - bf2f(hx)), ly = f2bf(acc.y - bf2f(hy));
    *reinterpret_cast<unsigned int*>(ohi + base) = (unsigned int)hx | ((unsigned int)hy << 16);
    *reinterpret_cast<unsigned int*>(olo + base) = (unsigned int)lx | ((unsigned int)ly << 16);
}

// ---------------- Collapsed layer 4 + pool + head ----------------
// logit_g = (1/c_g) * sum_{i in g} [ s[i] + sum_{src->i} s[src] + (1+deg_i)*beta ] + bc
// where s[i] = h3[i] . v,  v = Wc @ W4,  beta = Wc . b4.

__global__ __launch_bounds__(128) void vbeta_k(const float* __restrict__ W4,
                                               const float* __restrict__ b4,
                                               const float* __restrict__ Wc,
                                               float* __restrict__ vbeta) {
    int k = threadIdx.x;
    float acc = 0.f;
    for (int j = 0; j < D; ++j) acc = fmaf(Wc[j], W4[j * D + k], acc);
    vbeta[k] = acc;
    __shared__ float red[128];
    red[k] = Wc[k] * b4[k];
    __syncthreads();
    for (int st = 64; st > 0; st >>= 1) {
        if (k < st) red[k] += red[k + st];
        __syncthreads();
    }
    if (k == 0) vbeta[D] = red[0];
}

__global__ __launch_bounds__(256) void matvec_k(const unsigned short* __restrict__ hhi,
                                                const unsigned short* __restrict__ hlo,
                                                const float* __restrict__ vbeta,
                                                float* __restrict__ s) {
    int wid = threadIdx.x >> 6, lane = threadIdx.x & 63;
    int row = blockIdx.x * 4 + wid;
    const size_t base = (size_t)row * D + lane * 2;
    unsigned int h2 = *reinterpret_cast<const unsigned int*>(hhi + base);
    unsigned int l2 = *reinterpret_cast<const unsigned int*>(hlo + base);
    float hx = bf2f((unsigned short)h2) + bf2f((unsigned short)l2);
    float hy = bf2f((unsigned short)(h2 >> 16)) + bf2f((unsigned short)(l2 >> 16));
    const float2 vv = *reinterpret_cast<const float2*>(&vbeta[lane * 2]);
    float dot = fmaf(hx, vv.x, hy * vv.y);
#pragma unroll
    for (int d = 32; d > 0; d >>= 1) dot += __shfl_down(dot, d, 64);
    if (lane == 0) s[row] = dot;
}

__global__ __launch_bounds__(256) void sagg_k(const float* __restrict__ s,
                                              const int* __restrict__ start,
                                              const int* __restrict__ esrc,
                                              const float* __restrict__ vbeta,
                                              float* __restrict__ a) {
    int i = blockIdx.x * 256 + threadIdx.x;
    if (i >= N_NODES) return;
    int s0 = start[i], s1 = start[i + 1];
    float beta = vbeta[D];
    float acc = s[i] + (float)(1 + s1 - s0) * beta;
    for (int e = s0; e < s1; ++e) acc += s[esrc[e]];
    a[i] = acc;
}

__global__ __launch_bounds__(256) void spool_k(const float* __restrict__ a,
                                               const int* __restrict__ gstart,
                                               const float* __restrict__ bc,
                                               float* __restrict__ out) {
    int g = blockIdx.x;
    int lo = gstart[g], hi = gstart[g + 1];
    float acc = 0.f;
    for (int i = lo + threadIdx.x; i < hi; i += 256) acc += a[i];
    __shared__ float red[256];
    red[threadIdx.x] = acc;
    __syncthreads();
    for (int st = 128; st > 0; st >>= 1) {
        if (threadIdx.x < st) red[threadIdx.x] += red[threadIdx.x + st];
        __syncthreads();
    }
    if (threadIdx.x == 0) {
        float c = (float)max(hi - lo, 1);
        out[g] = 1.f / (1.f + expf(-(red[0] / c + bc[0])));
    }
}

// ---------------- Launch ----------------

extern "C" void kernel_launch(void* const* d_in, const int* in_sizes, int n_in,
                              void* d_out, int out_size, void* d_ws, size_t ws_size,
                              hipStream_t stream) {
    const float* x   = (const float*)d_in[0];
    const int* ei    = (const int*)d_in[1];
    const int* batch = (const int*)d_in[2];
    const float* W1  = (const float*)d_in[3];
    const float* b1  = (const float*)d_in[4];
    const float* W2  = (const float*)d_in[5];
    const float* b2  = (const float*)d_in[6];
    const float* W3  = (const float*)d_in[7];
    const float* b3  = (const float*)d_in[8];
    const float* W4  = (const float*)d_in[9];
    const float* b4  = (const float*)d_in[10];
    const float* Wc  = (const float*)d_in[11];
    const float* bc  = (const float*)d_in[12];
    float* out = (float*)d_out;

    const int* row = ei;             // sources
    const int* col = ei + N_EDGES;   // targets

    char* p = (char*)d_ws;
    float* t = (float*)p;            p += (size_t)N_NODES * D * 4;   // 51.2 MB
    unsigned short* hhi = (unsigned short*)p; p += (size_t)N_NODES * D * 2;  // 25.6 MB
    unsigned short* hlo = (unsigned short*)p; p += (size_t)N_NODES * D * 2;  // 25.6 MB
    unsigned short* whi = (unsigned short*)p; p += (size_t)D * D * 2;        // 32 KB
    unsigned short* wlo = (unsigned short*)p; p += (size_t)D * D * 2;        // 32 KB
    int* esrc = (int*)p;             p += (size_t)N_EDGES * 4;
    int* cstart = (int*)p;           p += ((N_NODES + 1) * 4 + 15) / 16 * 16;
    int* cfill = (int*)p;            p += (size_t)N_NODES * 4;
    int* psum = (int*)p;             p += ((NBLK_SCAN + 3) / 4) * 16;
    int* gstart = (int*)p;           p += 256;

    // scalar-path scratch lives in t (free after layer-3 aggregate consumes it)
    float* vbeta = t;
    float* s_arr = t + 256;
    float* a_arr = t + 256 + N_NODES;

    // ---- CSR build ----
    hipMemsetAsync(cfill, 0, (size_t)N_NODES * 4, stream);
    count_deg_k<<<(N_EDGES + 255) / 256, 256, 0, stream>>>(col, cfill);
    partial_k<<<NBLK_SCAN, 256, 0, stream>>>(cfill, psum);
    scanpart_k<<<1, 512, 0, stream>>>(psum);
    scan_scatter_k<<<NBLK_SCAN, 256, 0, stream>>>(cfill, psum, cstart);
    hipMemsetAsync(cfill, 0, (size_t)N_NODES * 4, stream);
    fill_csr_k<<<(N_EDGES + 255) / 256, 256, 0, stream>>>(row, col, cstart, cfill, esrc);

    // ---- graph bounds ----
    bounds_k<<<1, 128, 0, stream>>>(batch, gstart);

    const int ggrid = (N_NODES + BM - 1) / BM;       // 782
    const int agrid = (N_NODES + 3) / 4;             // 25000
    const int xn4 = N_NODES * D / 4;                 // 3.2M
    const int wn4 = D * D / 4;                       // 4096

    // ---- Layer 1 ----
    split_k<<<(xn4 + 255) / 256, 256, 0, stream>>>(x, hhi, hlo, xn4);
    split_k<<<(wn4 + 255) / 256, 256, 0, stream>>>(W1, whi, wlo, wn4);
    gemm_mfma_k<<<ggrid, 256, 0, stream>>>(hhi, hlo, whi, wlo, b1, t, N_NODES);
    aggregate_k<<<agrid, 256, 0, stream>>>(t, cstart, esrc, hhi, hlo, 1);
    // ---- Layer 2 ----
    split_k<<<(wn4 + 255) / 256, 256, 0, stream>>>(W2, whi, wlo, wn4);
    gemm_mfma_k<<<ggrid, 256, 0, stream>>>(hhi, hlo, whi, wlo, b2, t, N_NODES);
    aggregate_k<<<agrid, 256, 0, stream>>>(t, cstart, esrc, hhi, hlo, 1);
    // ---- Layer 3 ----
    split_k<<<(wn4 + 255) / 256, 256, 0, stream>>>(W3, whi, wlo, wn4);
    gemm_mfma_k<<<ggrid, 256, 0, stream>>>(hhi, hlo, whi, wlo, b3, t, N_NODES);
    aggregate_k<<<agrid, 256, 0, stream>>>(t, cstart, esrc, hhi, hlo, 1);

    // ---- Collapsed layer 4 + pool + head (reads hhi/hlo = h3) ----
    vbeta_k<<<1, 128, 0, stream>>>(W4, b4, Wc, vbeta);
    matvec_k<<<N_NODES / 4, 256, 0, stream>>>(hhi, hlo, vbeta, s_arr);
    sagg_k<<<(N_NODES + 255) / 256, 256, 0, stream>>>(s_arr, cstart, esrc, vbeta, a_arr);
    spool_k<<<N_GRAPHS, 256, 0, stream>>>(a_arr, gstart, bc, out);
}

// Round 15
// 416.324 us; speedup vs baseline: 1.7657x; 1.0646x over previous
//
#include <hip/hip_runtime.h>
#include <hip/hip_bf16.h>

#define N_NODES 100000
#define N_EDGES 600000
#define N_GRAPHS 64
#define D 128

#define NBLK_SCAN ((N_NODES + 255) / 256)  // 391

typedef __attribute__((ext_vector_type(8))) short short8v;
typedef __attribute__((ext_vector_type(4))) float float4v;

__device__ __forceinline__ unsigned short f2bf(float f) {
    unsigned int u = __float_as_uint(f);
    return (unsigned short)((u + 0x7FFF + ((u >> 16) & 1)) >> 16);  // RNE
}
__device__ __forceinline__ float bf2f(unsigned short h) {
    return __uint_as_float(((unsigned int)h) << 16);
}

// ---------------- CSR build ----------------

__global__ void count_deg_k(const int* __restrict__ col, int* __restrict__ cnt) {
    int e = blockIdx.x * blockDim.x + threadIdx.x;
    if (e < N_EDGES) atomicAdd(&cnt[col[e]], 1);
}

__global__ __launch_bounds__(256) void partial_k(const int* __restrict__ cnt,
                                                 int* __restrict__ psum) {
    int i = blockIdx.x * 256 + threadIdx.x;
    int v = (i < N_NODES) ? cnt[i] : 0;
#pragma unroll
    for (int d = 32; d > 0; d >>= 1) v += __shfl_down(v, d, 64);
    __shared__ int ws[4];
    if ((threadIdx.x & 63) == 0) ws[threadIdx.x >> 6] = v;
    __syncthreads();
    if (threadIdx.x == 0) psum[blockIdx.x] = ws[0] + ws[1] + ws[2] + ws[3];
}

__global__ __launch_bounds__(512) void scanpart_k(int* __restrict__ psum) {
    __shared__ int ls[512];
    int t = threadIdx.x;
    int v = (t < NBLK_SCAN) ? psum[t] : 0;
    ls[t] = v;
    __syncthreads();
    for (int d = 1; d < 512; d <<= 1) {
        int u = (t >= d) ? ls[t - d] : 0;
        __syncthreads();
        ls[t] += u;
        __syncthreads();
    }
    if (t < NBLK_SCAN) psum[t] = ls[t] - v;  // exclusive
}

__global__ __launch_bounds__(256) void scan_scatter_k(const int* __restrict__ cnt,
                                                      const int* __restrict__ psum,
                                                      int* __restrict__ start) {
    int b = blockIdx.x, t = threadIdx.x;
    int i = b * 256 + t;
    int v = (i < N_NODES) ? cnt[i] : 0;
    __shared__ int ls[256];
    ls[t] = v;
    __syncthreads();
    for (int d = 1; d < 256; d <<= 1) {
        int u = (t >= d) ? ls[t - d] : 0;
        __syncthreads();
        ls[t] += u;
        __syncthreads();
    }
    int incl = ls[t];
    int off = psum[b];
    if (i < N_NODES) start[i] = off + incl - v;
    if (i == N_NODES - 1) start[N_NODES] = off + incl;
}

__global__ void fill_csr_k(const int* __restrict__ row, const int* __restrict__ col,
                           const int* __restrict__ start, int* __restrict__ fill,
                           int* __restrict__ esrc) {
    int e = blockIdx.x * blockDim.x + threadIdx.x;
    if (e < N_EDGES) {
        int c = col[e];
        int p = atomicAdd(&fill[c], 1);
        esrc[start[c] + p] = row[e];
    }
}

// ---------------- graph segment bounds (batch is sorted) ----------------

__global__ __launch_bounds__(128) void bounds_k(const int* __restrict__ batch,
                                                int* __restrict__ gstart) {
    int g = threadIdx.x;
    if (g > N_GRAPHS) return;
    int lo = 0, hi = N_NODES;
    while (lo < hi) {
        int mid = (lo + hi) >> 1;
        if (batch[mid] < g) lo = mid + 1; else hi = mid;
    }
    gstart[g] = lo;
}

// ---------------- f32 -> (bf16 hi, bf16 lo) split (weights only) ----------------

__global__ __launch_bounds__(256) void split_k(const float* __restrict__ in,
                                               unsigned short* __restrict__ hi,
                                               unsigned short* __restrict__ lo, int n4) {
    int i = blockIdx.x * 256 + threadIdx.x;
    if (i >= n4) return;
    float4 v = reinterpret_cast<const float4*>(in)[i];
    ushort4 h, l;
    h.x = f2bf(v.x); l.x = f2bf(v.x - bf2f(h.x));
    h.y = f2bf(v.y); l.y = f2bf(v.y - bf2f(h.y));
    h.z = f2bf(v.z); l.z = f2bf(v.z - bf2f(h.z));
    h.w = f2bf(v.w); l.w = f2bf(v.w - bf2f(h.w));
    reinterpret_cast<ushort4*>(hi)[i] = h;
    reinterpret_cast<ushort4*>(lo)[i] = l;
}

// ---------------- Split-bf16 MFMA GEMM ----------------
// out[i][j] = bias[j] + sum_k (Ahi+Alo)[i][k]*(Whi+Wlo)[j][k]  (4 mfma terms,
// f32 accumulate). mfma_f32_16x16x32_bf16: A/B frag = 8 bf16/lane, non-k dim =
// lane&15, k = (lane>>4)*8 + j (same packing both operands -> internal k-perm
// cancels). C/D: row=(lane>>4)*4+reg, col=lane&15 (m89/m91-verified).
// Operands load DIRECT from global (A rows read once; W 64KB L2-hot).
// No barriers: epilogue de-scatters acc through per-wave-private LDS.

#define BM 128

__global__ __launch_bounds__(256) void gemm_mfma_k(
    const unsigned short* __restrict__ Ahi, const unsigned short* __restrict__ Alo,
    const unsigned short* __restrict__ Whi, const unsigned short* __restrict__ Wlo,
    const float* __restrict__ bias, float* __restrict__ out, int nrows) {
    __shared__ float swp[4][32][132];  // per-wave-private slices
    const int tid = threadIdx.x, l = tid & 63, wv = tid >> 6;
    const int bm0 = blockIdx.x * BM;
    const int g = l >> 4, li = l & 15;

    float4v acc[2][8];
#pragma unroll
    for (int rg = 0; rg < 2; ++rg)
#pragma unroll
        for (int cg = 0; cg < 8; ++cg) acc[rg][cg] = (float4v){0.f, 0.f, 0.f, 0.f};

    size_t abase[2];
#pragma unroll
    for (int rg = 0; rg < 2; ++rg)
        abase[rg] = (size_t)min(bm0 + wv * 32 + rg * 16 + li, nrows - 1) * D + g * 8;

#pragma unroll
    for (int kk = 0; kk < 4; ++kk) {
        const int k0 = kk * 32;
        short8v ah[2], al[2];
#pragma unroll
        for (int rg = 0; rg < 2; ++rg) {
            ah[rg] = *reinterpret_cast<const short8v*>(Ahi + abase[rg] + k0);
            al[rg] = *reinterpret_cast<const short8v*>(Alo + abase[rg] + k0);
        }
#pragma unroll
        for (int cg = 0; cg < 8; ++cg) {
            const size_t wb = (size_t)(cg * 16 + li) * D + g * 8 + k0;
            short8v wh = *reinterpret_cast<const short8v*>(Whi + wb);
            short8v wl = *reinterpret_cast<const short8v*>(Wlo + wb);
#pragma unroll
            for (int rg = 0; rg < 2; ++rg) {
                acc[rg][cg] = __builtin_amdgcn_mfma_f32_16x16x32_bf16(ah[rg], wh, acc[rg][cg], 0, 0, 0);
                acc[rg][cg] = __builtin_amdgcn_mfma_f32_16x16x32_bf16(al[rg], wh, acc[rg][cg], 0, 0, 0);
                acc[rg][cg] = __builtin_amdgcn_mfma_f32_16x16x32_bf16(ah[rg], wl, acc[rg][cg], 0, 0, 0);
                acc[rg][cg] = __builtin_amdgcn_mfma_f32_16x16x32_bf16(al[rg], wl, acc[rg][cg], 0, 0, 0);
            }
        }
    }

#pragma unroll
    for (int rg = 0; rg < 2; ++rg)
#pragma unroll
        for (int cg = 0; cg < 8; ++cg)
#pragma unroll
            for (int r = 0; r < 4; ++r)
                swp[wv][rg * 16 + g * 4 + r][cg * 16 + li] = acc[rg][cg][r];

    const int c4 = l & 31, rh = l >> 5;
    const float4 bias_v = *reinterpret_cast<const float4*>(&bias[c4 * 4]);
#pragma unroll
    for (int it = 0; it < 16; ++it) {
        int rowl = it * 2 + rh;
        int grow = bm0 + wv * 32 + rowl;
        if (grow < nrows) {
            float4 v = *reinterpret_cast<const float4*>(&swp[wv][rowl][c4 * 4]);
            v.x += bias_v.x; v.y += bias_v.y; v.z += bias_v.z; v.w += bias_v.w;
            *reinterpret_cast<float4*>(&out[(size_t)grow * D + c4 * 4]) = v;
        }
    }
}

// Layer-1 variant: A is f32 (x); split to bf16 hi/lo in registers (each row
// read exactly once -> deletes the separate 100MB split pass).
__global__ __launch_bounds__(256) void gemm_mfma_f32_k(
    const float* __restrict__ A,
    const unsigned short* __restrict__ Whi, const unsigned short* __restrict__ Wlo,
    const float* __restrict__ bias, float* __restrict__ out, int nrows) {
    __shared__ float swp[4][32][132];
    const int tid = threadIdx.x, l = tid & 63, wv = tid >> 6;
    const int bm0 = blockIdx.x * BM;
    const int g = l >> 4, li = l & 15;

    float4v acc[2][8];
#pragma unroll
    for (int rg = 0; rg < 2; ++rg)
#pragma unroll
        for (int cg = 0; cg < 8; ++cg) acc[rg][cg] = (float4v){0.f, 0.f, 0.f, 0.f};

    size_t abase[2];
#pragma unroll
    for (int rg = 0; rg < 2; ++rg)
        abase[rg] = (size_t)min(bm0 + wv * 32 + rg * 16 + li, nrows - 1) * D + g * 8;

#pragma unroll
    for (int kk = 0; kk < 4; ++kk) {
        const int k0 = kk * 32;
        short8v ah[2], al[2];
#pragma unroll
        for (int rg = 0; rg < 2; ++rg) {
            float4 f0 = *reinterpret_cast<const float4*>(A + abase[rg] + k0);
            float4 f1 = *reinterpret_cast<const float4*>(A + abase[rg] + k0 + 4);
            float fv[8] = {f0.x, f0.y, f0.z, f0.w, f1.x, f1.y, f1.z, f1.w};
#pragma unroll
            for (int j = 0; j < 8; ++j) {
                unsigned short h = f2bf(fv[j]);
                ah[rg][j] = (short)h;
                al[rg][j] = (short)f2bf(fv[j] - bf2f(h));
            }
        }
#pragma unroll
        for (int cg = 0; cg < 8; ++cg) {
            const size_t wb = (size_t)(cg * 16 + li) * D + g * 8 + k0;
            short8v wh = *reinterpret_cast<const short8v*>(Whi + wb);
            short8v wl = *reinterpret_cast<const short8v*>(Wlo + wb);
#pragma unroll
            for (int rg = 0; rg < 2; ++rg) {
                acc[rg][cg] = __builtin_amdgcn_mfma_f32_16x16x32_bf16(ah[rg], wh, acc[rg][cg], 0, 0, 0);
                acc[rg][cg] = __builtin_amdgcn_mfma_f32_16x16x32_bf16(al[rg], wh, acc[rg][cg], 0, 0, 0);
                acc[rg][cg] = __builtin_amdgcn_mfma_f32_16x16x32_bf16(ah[rg], wl, acc[rg][cg], 0, 0, 0);
                acc[rg][cg] = __builtin_amdgcn_mfma_f32_16x16x32_bf16(al[rg], wl, acc[rg][cg], 0, 0, 0);
            }
        }
    }

#pragma unroll
    for (int rg = 0; rg < 2; ++rg)
#pragma unroll
        for (int cg = 0; cg < 8; ++cg)
#pragma unroll
            for (int r = 0; r < 4; ++r)
                swp[wv][rg * 16 + g * 4 + r][cg * 16 + li] = acc[rg][cg][r];

    const int c4 = l & 31, rh = l >> 5;
    const float4 bias_v = *reinterpret_cast<const float4*>(&bias[c4 * 4]);
#pragma unroll
    for (int it = 0; it < 16; ++it) {
        int rowl = it * 2 + rh;
        int grow = bm0 + wv * 32 + rowl;
        if (grow < nrows) {
            float4 v = *reinterpret_cast<const float4*>(&swp[wv][rowl][c4 * 4]);
            v.x += bias_v.x; v.y += bias_v.y; v.z += bias_v.z; v.w += bias_v.w;
            *reinterpret_cast<float4*>(&out[(size_t)grow * D + c4 * 4]) = v;
        }
    }
}

// ---------------- Aggregation: (t f32 gather) -> bf16 hi/lo pair ----------------
// 2 nodes per wave (32 lanes x float4 = one 512B request per row), 4-edge
// unroll -> 4 independent gather chains per half-wave.

__global__ __launch_bounds__(256) void aggregate_k(const float* __restrict__ t,
                                                   const int* __restrict__ start,
                                                   const int* __restrict__ esrc,
                                                   unsigned short* __restrict__ ohi,
                                                   unsigned short* __restrict__ olo,
                                                   int do_relu) {
    const int wv = threadIdx.x >> 6, l = threadIdx.x & 63;
    const int half = l >> 5, li = l & 31;
    const int node = blockIdx.x * 8 + wv * 2 + half;
    if (node >= N_NODES) return;
    const int s = start[node], e = start[node + 1];
    const size_t base = ((size_t)node << 7) + 4 * li;
    float4 acc = *reinterpret_cast<const float4*>(t + base);  // self loop
    int i = s;
    for (; i + 3 < e; i += 4) {
        const float4 v0 = *reinterpret_cast<const float4*>(t + (((size_t)esrc[i] << 7) + 4 * li));
        const float4 v1 = *reinterpret_cast<const float4*>(t + (((size_t)esrc[i + 1] << 7) + 4 * li));
        const float4 v2 = *reinterpret_cast<const float4*>(t + (((size_t)esrc[i + 2] << 7) + 4 * li));
        const float4 v3 = *reinterpret_cast<const float4*>(t + (((size_t)esrc[i + 3] << 7) + 4 * li));
        acc.x += (v0.x + v1.x) + (v2.x + v3.x);
        acc.y += (v0.y + v1.y) + (v2.y + v3.y);
        acc.z += (v0.z + v1.z) + (v2.z + v3.z);
        acc.w += (v0.w + v1.w) + (v2.w + v3.w);
    }
    for (; i < e; ++i) {
        const float4 v = *reinterpret_cast<const float4*>(t + (((size_t)esrc[i] << 7) + 4 * li));
        acc.x += v.x; acc.y += v.y; acc.z += v.z; acc.w += v.w;
    }
    if (do_relu) {
        acc.x = fmaxf(acc.x, 0.f);
        acc.y = fmaxf(acc.y, 0.f);
        acc.z = fmaxf(acc.z, 0.f);
        acc.w = fmaxf(acc.w, 0.f);
    }
    ushort4 h, lo4;
    h.x = f2bf(acc.x); lo4.x = f2bf(acc.x - bf2f(h.x));
    h.y = f2bf(acc.y); lo4.y = f2bf(acc.y - bf2f(h.y));
    h.z = f2bf(acc.z); lo4.z = f2bf(acc.z - bf2f(h.z));
    h.w = f2bf(acc.w); lo4.w = f2bf(acc.w - bf2f(h.w));
    *reinterpret_cast<ushort4*>(ohi + base) = h;
    *reinterpret_cast<ushort4*>(olo + base) = lo4;
}

// ---------------- Collapsed layer 4 + pool + head ----------------
// logit_g = (1/c_g) * sum_{i in g} [ s[i] + sum_{src->i} s[src] + (1+deg_i)*beta ] + bc
// where s[i] = h3[i] . v,  v = Wc @ W4,  beta = Wc . b4.

__global__ __launch_bounds__(128) void vbeta_k(const float* __restrict__ W4,
                                               const float* __restrict__ b4,
                                               const float* __restrict__ Wc,
                                               float* __restrict__ vbeta) {
    int k = threadIdx.x;
    float acc = 0.f;
    for (int j = 0; j < D; ++j) acc = fmaf(Wc[j], W4[j * D + k], acc);
    vbeta[k] = acc;
    __shared__ float red[128];
    red[k] = Wc[k] * b4[k];
    __syncthreads();
    for (int st = 64; st > 0; st >>= 1) {
        if (k < st) red[k] += red[k + st];
        __syncthreads();
    }
    if (k == 0) vbeta[D] = red[0];
}

__global__ __launch_bounds__(256) void matvec_k(const unsigned short* __restrict__ hhi,
                                                const unsigned short* __restrict__ hlo,
                                                const float* __restrict__ vbeta,
                                                float* __restrict__ s) {
    int wid = threadIdx.x >> 6, lane = threadIdx.x & 63;
    int row = blockIdx.x * 4 + wid;
    const size_t base = (size_t)row * D + lane * 2;
    unsigned int h2 = *reinterpret_cast<const unsigned int*>(hhi + base);
    unsigned int l2 = *reinterpret_cast<const unsigned int*>(hlo + base);
    float hx = bf2f((unsigned short)h2) + bf2f((unsigned short)l2);
    float hy = bf2f((unsigned short)(h2 >> 16)) + bf2f((unsigned short)(l2 >> 16));
    const float2 vv = *reinterpret_cast<const float2*>(&vbeta[lane * 2]);
    float dot = fmaf(hx, vv.x, hy * vv.y);
#pragma unroll
    for (int d = 32; d > 0; d >>= 1) dot += __shfl_down(dot, d, 64);
    if (lane == 0) s[row] = dot;
}

__global__ __launch_bounds__(256) void sagg_k(const float* __restrict__ s,
                                              const int* __restrict__ start,
                                              const int* __restrict__ esrc,
                                              const float* __restrict__ vbeta,
                                              float* __restrict__ a) {
    int i = blockIdx.x * 256 + threadIdx.x;
    if (i >= N_NODES) return;
    int s0 = start[i], s1 = start[i + 1];
    float beta = vbeta[D];
    float acc = s[i] + (float)(1 + s1 - s0) * beta;
    for (int e = s0; e < s1; ++e) acc += s[esrc[e]];
    a[i] = acc;
}

__global__ __launch_bounds__(256) void spool_k(const float* __restrict__ a,
                                               const int* __restrict__ gstart,
                                               const float* __restrict__ bc,
                                               float* __restrict__ out) {
    int g = blockIdx.x;
    int lo = gstart[g], hi = gstart[g + 1];
    float acc = 0.f;
    for (int i = lo + threadIdx.x; i < hi; i += 256) acc += a[i];
    __shared__ float red[256];
    red[threadIdx.x] = acc;
    __syncthreads();
    for (int st = 128; st > 0; st >>= 1) {
        if (threadIdx.x < st) red[threadIdx.x] += red[threadIdx.x + st];
        __syncthreads();
    }
    if (threadIdx.x == 0) {
        float c = (float)max(hi - lo, 1);
        out[g] = 1.f / (1.f + expf(-(red[0] / c + bc[0])));
    }
}

// ---------------- Launch ----------------

extern "C" void kernel_launch(void* const* d_in, const int* in_sizes, int n_in,
                              void* d_out, int out_size, void* d_ws, size_t ws_size,
                              hipStream_t stream) {
    const float* x   = (const float*)d_in[0];
    const int* ei    = (const int*)d_in[1];
    const int* batch = (const int*)d_in[2];
    const float* W1  = (const float*)d_in[3];
    const float* b1  = (const float*)d_in[4];
    const float* W2  = (const float*)d_in[5];
    const float* b2  = (const float*)d_in[6];
    const float* W3  = (const float*)d_in[7];
    const float* b3  = (const float*)d_in[8];
    const float* W4  = (const float*)d_in[9];
    const float* b4  = (const float*)d_in[10];
    const float* Wc  = (const float*)d_in[11];
    const float* bc  = (const float*)d_in[12];
    float* out = (float*)d_out;

    const int* row = ei;             // sources
    const int* col = ei + N_EDGES;   // targets

    char* p = (char*)d_ws;
    float* t = (float*)p;            p += (size_t)N_NODES * D * 4;   // 51.2 MB
    unsigned short* hhi = (unsigned short*)p; p += (size_t)N_NODES * D * 2;  // 25.6 MB
    unsigned short* hlo = (unsigned short*)p; p += (size_t)N_NODES * D * 2;  // 25.6 MB
    unsigned short* whi = (unsigned short*)p; p += (size_t)D * D * 2;        // 32 KB
    unsigned short* wlo = (unsigned short*)p; p += (size_t)D * D * 2;        // 32 KB
    int* esrc = (int*)p;             p += (size_t)N_EDGES * 4;
    int* cstart = (int*)p;           p += ((N_NODES + 1) * 4 + 15) / 16 * 16;
    int* cfill = (int*)p;            p += (size_t)N_NODES * 4;
    int* psum = (int*)p;             p += ((NBLK_SCAN + 3) / 4) * 16;
    int* gstart = (int*)p;           p += 256;

    // scalar-path scratch lives in t (free after layer-3 aggregate consumes it)
    float* vbeta = t;
    float* s_arr = t + 256;
    float* a_arr = t + 256 + N_NODES;

    // ---- CSR build ----
    hipMemsetAsync(cfill, 0, (size_t)N_NODES * 4, stream);
    count_deg_k<<<(N_EDGES + 255) / 256, 256, 0, stream>>>(col, cfill);
    partial_k<<<NBLK_SCAN, 256, 0, stream>>>(cfill, psum);
    scanpart_k<<<1, 512, 0, stream>>>(psum);
    scan_scatter_k<<<NBLK_SCAN, 256, 0, stream>>>(cfill, psum, cstart);
    hipMemsetAsync(cfill, 0, (size_t)N_NODES * 4, stream);
    fill_csr_k<<<(N_EDGES + 255) / 256, 256, 0, stream>>>(row, col, cstart, cfill, esrc);

    // ---- graph bounds ----
    bounds_k<<<1, 128, 0, stream>>>(batch, gstart);

    const int ggrid = (N_NODES + BM - 1) / BM;       // 782
    const int agrid = (N_NODES + 7) / 8;             // 12500
    const int wn4 = D * D / 4;                       // 4096

    // ---- Layer 1 (x split in-register inside the gemm) ----
    split_k<<<(wn4 + 255) / 256, 256, 0, stream>>>(W1, whi, wlo, wn4);
    gemm_mfma_f32_k<<<ggrid, 256, 0, stream>>>(x, whi, wlo, b1, t, N_NODES);
    aggregate_k<<<agrid, 256, 0, stream>>>(t, cstart, esrc, hhi, hlo, 1);
    // ---- Layer 2 ----
    split_k<<<(wn4 + 255) / 256, 256, 0, stream>>>(W2, whi, wlo, wn4);
    gemm_mfma_k<<<ggrid, 256, 0, stream>>>(hhi, hlo, whi, wlo, b2, t, N_NODES);
    aggregate_k<<<agrid, 256, 0, stream>>>(t, cstart, esrc, hhi, hlo, 1);
    // ---- Layer 3 ----
    split_k<<<(wn4 + 255) / 256, 256, 0, stream>>>(W3, whi, wlo, wn4);
    gemm_mfma_k<<<ggrid, 256, 0, stream>>>(hhi, hlo, whi, wlo, b3, t, N_NODES);
    aggregate_k<<<agrid, 256, 0, stream>>>(t, cstart, esrc, hhi, hlo, 1);

    // ---- Collapsed layer 4 + pool + head (reads hhi/hlo = h3) ----
    vbeta_k<<<1, 128, 0, stream>>>(W4, b4, Wc, vbeta);
    matvec_k<<<N_NODES / 4, 256, 0, stream>>>(hhi, hlo, vbeta, s_arr);
    sagg_k<<<(N_NODES + 255) / 256, 256, 0, stream>>>(s_arr, cstart, esrc, vbeta, a_arr);
    spool_k<<<N_GRAPHS, 256, 0, stream>>>(a_arr, gstart, bc, out);
}